// Round 6
// baseline (116.879 us; speedup 1.0000x reference)
//
#include <hip/hip_runtime.h>

// CNS residuals: vars (B=8, C=4, T=64, X=128, Y=128) f32
// out (B=8, 2, 62, 126, 126) f32: [mass, mom_x+mom_y] on inner region.
// R6: LDS-stage the t-center plane (only data with intra-block reuse).
// Block = 448 thr = 14 x-rows x 32 y-groups at one (b,tp). Stage 66 rows
// (R16/U18/V16/P16) = 33KB LDS; compute reads aligned ds_read_b128 chunks
// + shuffle windows. Global loads/thread 20 -> 11 (5 stage + 6 t+-1).
// Grid 4464 = 8 XCD x 558 (= one batch b per XCD). NT stores kept.

typedef float vf4 __attribute__((ext_vector_type(4)));
typedef float vf4u __attribute__((ext_vector_type(4), aligned(4)));

__device__ __forceinline__ vf4 ld4(const float* p) {
    return *reinterpret_cast<const vf4u*>(p);
}

struct Win { vf4 lo, hi; };
// window covers y' = 4j-1 .. 4j+6; element e at shift s -> index 2+e+s
#define SH(w, s) __builtin_shufflevector((w).lo, (w).hi, 2 + (s), 3 + (s), 4 + (s), 5 + (s))

// shifts in [-1,1]: own chunk + 2 down-shuffled edge elems
__device__ __forceinline__ Win mkwin(vf4 c, float mHi) {
    const float dn0 = __shfl_down(c.x, 1) * mHi;
    const float dn1 = __shfl_down(c.y, 1) * mHi;
    Win w;
    w.lo = (vf4){0.0f, c.x, c.y, c.z};
    w.hi = (vf4){c.w, dn0, dn1, 0.0f};
    return w;
}
// shifts in [-2,2]
__device__ __forceinline__ Win mkwin2(vf4 c, float mLo, float mHi) {
    const float up3 = __shfl_up(c.w, 1) * mLo;
    const float dn0 = __shfl_down(c.x, 1) * mHi;
    const float dn1 = __shfl_down(c.y, 1) * mHi;
    const float dn2 = __shfl_down(c.z, 1) * mHi;
    Win w;
    w.lo = (vf4){up3, c.x, c.y, c.z};
    w.hi = (vf4){c.w, dn0, dn1, dn2};
    return w;
}
// center 4 values y = 4j+1..4j+4 from aligned chunk (replaces misaligned ld)
__device__ __forceinline__ vf4 ctr(vf4 c, float mHi) {
    const float dn0 = __shfl_down(c.x, 1) * mHi;
    return (vf4){c.y, c.z, c.w, dn0};
}

__global__ __launch_bounds__(448, 7) void cns_residuals_kernel(
    const float* __restrict__ vars,
    const float* __restrict__ s_dx, const float* __restrict__ s_dt,
    const float* __restrict__ s_eta, const float* __restrict__ s_zeta,
    float* __restrict__ out)
{
    __shared__ float lds[66 * 128];   // R[0,16) U[16,34) V[34,50) P[50,66)

    const float dx = s_dx[0], dt = s_dt[0], eta = s_eta[0], zeta = s_zeta[0];
    const float bulk = zeta + eta * (1.0f / 3.0f);
    const float c1 = 2.0f * dx * dx;
    const float c2 = 2.0f * dt * dx;
    const float c3 = 4.0f * dt;
    const float c4 = 2.0f * dt;

    // bijective XCD swizzle: nwg = 4464 = 8 * 558; XCD k <-> batch b = k
    const int i = blockIdx.x;
    const int lb = (i & 7) * 558 + (i >> 3);
    int r = lb;
    const int xg = r % 9; r /= 9;          // x-group (14 rows each)
    const int tp = r % 62; const int b = r / 62;
    const int xp0 = xg * 14;
    const int x0 = xp0 + 1;                // input row of first output
    const int t = tp + 1;

    const int j  = threadIdx.x & 31;       // y-group: outputs y = 4j+1..4j+4
    const int xl = threadIdx.x >> 5;       // 0..13 local x-row
    const int q  = 4 * j;

    const size_t plane = 16384;
    const size_t cstr  = (size_t)64 * plane;
    const float* cbase = vars + (size_t)b * 4 * cstr + (size_t)t * plane;

    // ---- stage center plane: 66 rows x 128 floats ----
    for (int c = threadIdx.x; c < 66 * 32; c += 448) {
        const int sr = c >> 5;             // section row 0..65
        const int cw = c & 31;             // 16B chunk in row
        int ch, grow;
        if (sr < 16)      { ch = 0; grow = x0 - 1 + sr; }
        else if (sr < 34) { ch = 1; grow = x0 - 2 + (sr - 16); }
        else if (sr < 50) { ch = 2; grow = x0 - 1 + (sr - 34); }
        else              { ch = 3; grow = x0 - 1 + (sr - 50); }
        vf4 val = {0.0f, 0.0f, 0.0f, 0.0f};
        if ((unsigned)grow < 128u)
            val = ld4(cbase + (size_t)ch * cstr + ((size_t)grow << 7) + 4 * cw);
        *reinterpret_cast<vf4*>(&lds[sr * 128 + 4 * cw]) = val;
    }
    __syncthreads();

    const float mLo = (j == 0)  ? 0.0f : 1.0f;
    const float mHi = (j == 31) ? 0.0f : 1.0f;

    // ---- LDS reads: 14 aligned ds_read_b128 ----
    const float* LR = &lds[(xl + 1) * 128 + q];          // R row x
    const float* LU = &lds[(16 + xl + 2) * 128 + q];     // U row x
    const float* LV = &lds[(34 + xl + 1) * 128 + q];     // V row x
    const float* LP = &lds[(50 + xl + 1) * 128 + q];     // P row x

    const vf4 cR   = ld4(LR);
    const vf4 cRp  = ld4(LR + 128), cRm  = ld4(LR - 128);
    const vf4 cU   = ld4(LU);
    const vf4 cUp  = ld4(LU + 128), cUm  = ld4(LU - 128);
    const vf4 cUp2 = ld4(LU + 256), cUm2 = ld4(LU - 256);
    const vf4 cV   = ld4(LV);
    const vf4 cVp  = ld4(LV + 128), cVm  = ld4(LV - 128);
    const vf4 cP   = ld4(LP);
    const vf4 cPp  = ld4(LP + 128), cPm  = ld4(LP - 128);

    // ---- direct global t+-1 loads (no intra-block reuse) ----
    const int x = x0 + xl;
    const float* gb = cbase + ((size_t)x << 7) + (q + 1);
    const vf4 rtp = ld4(gb + plane),             rtm = ld4(gb - plane);
    const vf4 utp = ld4(gb + cstr + plane),      utm = ld4(gb + cstr - plane);
    const vf4 vtp = ld4(gb + 2 * cstr + plane),  vtm = ld4(gb + 2 * cstr - plane);

    // ---- windows ----
    const Win Rw0 = mkwin(cR, mHi);
    const Win Uw0 = mkwin(cU, mHi);
    const Win Uwm = mkwin(cUm, mHi), Uw1 = mkwin(cUp, mHi);
    const Win Vw0 = mkwin2(cV, mLo, mHi);
    const Win Vwm = mkwin(cVm, mHi), Vw1 = mkwin(cVp, mHi);
    const Win Pw0 = mkwin(cP, mHi);
    const vf4 rxp = ctr(cRp, mHi), rxm = ctr(cRm, mHi);
    const vf4 pxp = ctr(cPp, mHi), pxm = ctr(cPm, mHi);
    const vf4 uxp2 = ctr(cUp2, mHi), uxm2 = ctr(cUm2, mHi);

    const vf4 rho = SH(Rw0, 0);
    const vf4 u   = SH(Uw0, 0);
    const vf4 v   = SH(Vw0, 0);

    const vf4 uxp = SH(Uw1, 0), uxm = SH(Uwm, 0);
    const vf4 uyp = SH(Uw0, 1), uym = SH(Uw0, -1);
    const vf4 vxp = SH(Vw1, 0), vxm = SH(Vwm, 0);
    const vf4 vyp = SH(Vw0, 1), vym = SH(Vw0, -1);

    const vf4 Dt_rho = rtp - rtm;
    const vf4 Dx_rho = rxp - rxm;
    const vf4 Dy_rho = SH(Rw0, 1) - SH(Rw0, -1);
    const vf4 Dx_u = uxp - uxm, Dy_u = uyp - uym;
    const vf4 Dx_v = vxp - vxm, Dy_v = vyp - vym;

    const vf4 mass = Dt_rho * dx + rho * (Dx_u + Dy_v) * dt
                   + u * Dx_rho * dt + v * Dy_rho * dt;

    const vf4 Dt_u = utp - utm, Dt_v = vtp - vtm;
    const vf4 Dx_p = pxp - pxm;
    const vf4 Dy_p = SH(Pw0, 1) - SH(Pw0, -1);
    const vf4 lap_u = uxp + uxm + uyp + uym - 4.0f * u;
    const vf4 lap_v = vxp + vxm + vyp + vym - 4.0f * v;

    const vf4 Dx_div = uxp2 - 2.0f * u + uxm2
                     + SH(Vw1, 1) - SH(Vw1, -1)
                     - SH(Vwm, 1) + SH(Vwm, -1);
    const vf4 Dy_div = SH(Vw0, 2) - 2.0f * v + SH(Vw0, -2)
                     + SH(Uw1, 1) - SH(Uwm, 1)
                     - SH(Uw1, -1) + SH(Uwm, -1);

    const vf4 mom = rho * (Dt_u + Dt_v) * c1
                  + (u * (Dx_u + Dx_v) + v * (Dy_u + Dy_v)) * c2
                  + (Dx_p + Dy_p) * c2
                  - eta * (lap_u + lap_v) * c3
                  - bulk * (Dx_div + Dy_div) * c4;

    const size_t oplane = 126 * 126;
    const size_t ocstr  = (size_t)62 * oplane;
    const int xp = xp0 + xl;
    float* o1 = out + (size_t)b * 2 * ocstr + (size_t)tp * oplane
              + (size_t)xp * 126 + 4 * j;
    float* o2 = o1 + ocstr;
    if (j < 31) {
        __builtin_nontemporal_store(mass, reinterpret_cast<vf4u*>(o1));
        __builtin_nontemporal_store(mom,  reinterpret_cast<vf4u*>(o2));
    } else {  // y=127,128 out of range; store only 2
        __builtin_nontemporal_store(mass[0], o1);
        __builtin_nontemporal_store(mass[1], o1 + 1);
        __builtin_nontemporal_store(mom[0],  o2);
        __builtin_nontemporal_store(mom[1],  o2 + 1);
    }
}

extern "C" void kernel_launch(void* const* d_in, const int* in_sizes, int n_in,
                              void* d_out, int out_size, void* d_ws, size_t ws_size,
                              hipStream_t stream) {
    const float* vars   = (const float*)d_in[0];
    const float* s_dx   = (const float*)d_in[1];
    const float* s_dt   = (const float*)d_in[2];
    const float* s_eta  = (const float*)d_in[3];
    const float* s_zeta = (const float*)d_in[4];
    float* out = (float*)d_out;

    const int grid = 4464;  // 9 * 62 * 8 blocks of 448 threads
    hipLaunchKernelGGL(cns_residuals_kernel, dim3(grid), dim3(448), 0, stream,
                       vars, s_dx, s_dt, s_eta, s_zeta, out);
}

// Round 7
// 48.140 us; speedup vs baseline: 2.4279x; 2.4279x over previous
//
#include <hip/hip_runtime.h>

// CNS residuals: vars (B=8, C=4, T=64, X=128, Y=128) f32
// out (B=8, 2, 62, 126, 126) f32: [mass, mom_x+mom_y] on inner region.
// R7 = R6 structure with fixed launch bounds (R6's (448,7) forced VGPR=36 ->
// 400MB scratch spill traffic). LDS-stage center t-plane (66 rows, 33KB);
// block = 448 thr = 14 x-rows x 32 y-groups; global loads/thread 20 -> 11.
// Grid 4464 = 8 XCD x 558 (one batch b per XCD). NT stores kept.

typedef float vf4 __attribute__((ext_vector_type(4)));
typedef float vf4u __attribute__((ext_vector_type(4), aligned(4)));

__device__ __forceinline__ vf4 ld4(const float* p) {
    return *reinterpret_cast<const vf4u*>(p);
}

struct Win { vf4 lo, hi; };
// window covers y' = 4j-1 .. 4j+6; element e at shift s -> index 2+e+s
#define SH(w, s) __builtin_shufflevector((w).lo, (w).hi, 2 + (s), 3 + (s), 4 + (s), 5 + (s))

// shifts in [-1,1]: own chunk + 2 down-shuffled edge elems
__device__ __forceinline__ Win mkwin(vf4 c, float mHi) {
    const float dn0 = __shfl_down(c.x, 1) * mHi;
    const float dn1 = __shfl_down(c.y, 1) * mHi;
    Win w;
    w.lo = (vf4){0.0f, c.x, c.y, c.z};
    w.hi = (vf4){c.w, dn0, dn1, 0.0f};
    return w;
}
// shifts in [-2,2]
__device__ __forceinline__ Win mkwin2(vf4 c, float mLo, float mHi) {
    const float up3 = __shfl_up(c.w, 1) * mLo;
    const float dn0 = __shfl_down(c.x, 1) * mHi;
    const float dn1 = __shfl_down(c.y, 1) * mHi;
    const float dn2 = __shfl_down(c.z, 1) * mHi;
    Win w;
    w.lo = (vf4){up3, c.x, c.y, c.z};
    w.hi = (vf4){c.w, dn0, dn1, dn2};
    return w;
}
// center 4 values y = 4j+1..4j+4 from aligned chunk
__device__ __forceinline__ vf4 ctr(vf4 c, float mHi) {
    const float dn0 = __shfl_down(c.x, 1) * mHi;
    return (vf4){c.y, c.z, c.w, dn0};
}

__global__ __launch_bounds__(448, 2) void cns_residuals_kernel(
    const float* __restrict__ vars,
    const float* __restrict__ s_dx, const float* __restrict__ s_dt,
    const float* __restrict__ s_eta, const float* __restrict__ s_zeta,
    float* __restrict__ out)
{
    __shared__ float lds[66 * 128];   // R[0,16) U[16,34) V[34,50) P[50,66)

    const float dx = s_dx[0], dt = s_dt[0], eta = s_eta[0], zeta = s_zeta[0];
    const float bulk = zeta + eta * (1.0f / 3.0f);
    const float c1 = 2.0f * dx * dx;
    const float c2 = 2.0f * dt * dx;
    const float c3 = 4.0f * dt;
    const float c4 = 2.0f * dt;

    // bijective XCD swizzle: nwg = 4464 = 8 * 558; XCD k <-> batch b = k
    const int i = blockIdx.x;
    const int lb = (i & 7) * 558 + (i >> 3);
    int r = lb;
    const int xg = r % 9; r /= 9;          // x-group (14 rows each)
    const int tp = r % 62; const int b = r / 62;
    const int xp0 = xg * 14;
    const int x0 = xp0 + 1;                // input row of first output
    const int t = tp + 1;

    const int j  = threadIdx.x & 31;       // y-group: outputs y = 4j+1..4j+4
    const int xl = threadIdx.x >> 5;       // 0..13 local x-row
    const int q  = 4 * j;

    const size_t plane = 16384;
    const size_t cstr  = (size_t)64 * plane;
    const float* cbase = vars + (size_t)b * 4 * cstr + (size_t)t * plane;

    // ---- stage center plane: 66 rows x 128 floats ----
    for (int c = threadIdx.x; c < 66 * 32; c += 448) {
        const int sr = c >> 5;             // section row 0..65
        const int cw = c & 31;             // 16B chunk in row
        int ch, grow;
        if (sr < 16)      { ch = 0; grow = x0 - 1 + sr; }
        else if (sr < 34) { ch = 1; grow = x0 - 2 + (sr - 16); }
        else if (sr < 50) { ch = 2; grow = x0 - 1 + (sr - 34); }
        else              { ch = 3; grow = x0 - 1 + (sr - 50); }
        vf4 val = {0.0f, 0.0f, 0.0f, 0.0f};
        if ((unsigned)grow < 128u)
            val = ld4(cbase + (size_t)ch * cstr + ((size_t)grow << 7) + 4 * cw);
        *reinterpret_cast<vf4*>(&lds[sr * 128 + 4 * cw]) = val;
    }
    __syncthreads();

    const float mLo = (j == 0)  ? 0.0f : 1.0f;
    const float mHi = (j == 31) ? 0.0f : 1.0f;

    // ---- LDS reads: 13 aligned ds_read_b128 ----
    const float* LR = &lds[(xl + 1) * 128 + q];          // R row x
    const float* LU = &lds[(16 + xl + 2) * 128 + q];     // U row x
    const float* LV = &lds[(34 + xl + 1) * 128 + q];     // V row x
    const float* LP = &lds[(50 + xl + 1) * 128 + q];     // P row x

    const vf4 cR   = ld4(LR);
    const vf4 cRp  = ld4(LR + 128), cRm  = ld4(LR - 128);
    const vf4 cU   = ld4(LU);
    const vf4 cUp  = ld4(LU + 128), cUm  = ld4(LU - 128);
    const vf4 cUp2 = ld4(LU + 256), cUm2 = ld4(LU - 256);
    const vf4 cV   = ld4(LV);
    const vf4 cVp  = ld4(LV + 128), cVm  = ld4(LV - 128);
    const vf4 cP   = ld4(LP);
    const vf4 cPp  = ld4(LP + 128), cPm  = ld4(LP - 128);

    // ---- direct global t+-1 loads (no intra-block reuse) ----
    const int x = x0 + xl;
    const float* gb = cbase + ((size_t)x << 7) + (q + 1);
    const vf4 rtp = ld4(gb + plane),             rtm = ld4(gb - plane);
    const vf4 utp = ld4(gb + cstr + plane),      utm = ld4(gb + cstr - plane);
    const vf4 vtp = ld4(gb + 2 * cstr + plane),  vtm = ld4(gb + 2 * cstr - plane);

    // ---- windows ----
    const Win Rw0 = mkwin(cR, mHi);
    const Win Uw0 = mkwin(cU, mHi);
    const Win Uwm = mkwin(cUm, mHi), Uw1 = mkwin(cUp, mHi);
    const Win Vw0 = mkwin2(cV, mLo, mHi);
    const Win Vwm = mkwin(cVm, mHi), Vw1 = mkwin(cVp, mHi);
    const Win Pw0 = mkwin(cP, mHi);
    const vf4 rxp = ctr(cRp, mHi), rxm = ctr(cRm, mHi);
    const vf4 pxp = ctr(cPp, mHi), pxm = ctr(cPm, mHi);
    const vf4 uxp2 = ctr(cUp2, mHi), uxm2 = ctr(cUm2, mHi);

    const vf4 rho = SH(Rw0, 0);
    const vf4 u   = SH(Uw0, 0);
    const vf4 v   = SH(Vw0, 0);

    const vf4 uxp = SH(Uw1, 0), uxm = SH(Uwm, 0);
    const vf4 uyp = SH(Uw0, 1), uym = SH(Uw0, -1);
    const vf4 vxp = SH(Vw1, 0), vxm = SH(Vwm, 0);
    const vf4 vyp = SH(Vw0, 1), vym = SH(Vw0, -1);

    const vf4 Dt_rho = rtp - rtm;
    const vf4 Dx_rho = rxp - rxm;
    const vf4 Dy_rho = SH(Rw0, 1) - SH(Rw0, -1);
    const vf4 Dx_u = uxp - uxm, Dy_u = uyp - uym;
    const vf4 Dx_v = vxp - vxm, Dy_v = vyp - vym;

    const vf4 mass = Dt_rho * dx + rho * (Dx_u + Dy_v) * dt
                   + u * Dx_rho * dt + v * Dy_rho * dt;

    const vf4 Dt_u = utp - utm, Dt_v = vtp - vtm;
    const vf4 Dx_p = pxp - pxm;
    const vf4 Dy_p = SH(Pw0, 1) - SH(Pw0, -1);
    const vf4 lap_u = uxp + uxm + uyp + uym - 4.0f * u;
    const vf4 lap_v = vxp + vxm + vyp + vym - 4.0f * v;

    const vf4 Dx_div = uxp2 - 2.0f * u + uxm2
                     + SH(Vw1, 1) - SH(Vw1, -1)
                     - SH(Vwm, 1) + SH(Vwm, -1);
    const vf4 Dy_div = SH(Vw0, 2) - 2.0f * v + SH(Vw0, -2)
                     + SH(Uw1, 1) - SH(Uwm, 1)
                     - SH(Uw1, -1) + SH(Uwm, -1);

    const vf4 mom = rho * (Dt_u + Dt_v) * c1
                  + (u * (Dx_u + Dx_v) + v * (Dy_u + Dy_v)) * c2
                  + (Dx_p + Dy_p) * c2
                  - eta * (lap_u + lap_v) * c3
                  - bulk * (Dx_div + Dy_div) * c4;

    const size_t oplane = 126 * 126;
    const size_t ocstr  = (size_t)62 * oplane;
    const int xp = xp0 + xl;
    float* o1 = out + (size_t)b * 2 * ocstr + (size_t)tp * oplane
              + (size_t)xp * 126 + 4 * j;
    float* o2 = o1 + ocstr;
    if (j < 31) {
        __builtin_nontemporal_store(mass, reinterpret_cast<vf4u*>(o1));
        __builtin_nontemporal_store(mom,  reinterpret_cast<vf4u*>(o2));
    } else {  // y=127,128 out of range; store only 2
        __builtin_nontemporal_store(mass[0], o1);
        __builtin_nontemporal_store(mass[1], o1 + 1);
        __builtin_nontemporal_store(mom[0],  o2);
        __builtin_nontemporal_store(mom[1],  o2 + 1);
    }
}

extern "C" void kernel_launch(void* const* d_in, const int* in_sizes, int n_in,
                              void* d_out, int out_size, void* d_ws, size_t ws_size,
                              hipStream_t stream) {
    const float* vars   = (const float*)d_in[0];
    const float* s_dx   = (const float*)d_in[1];
    const float* s_dt   = (const float*)d_in[2];
    const float* s_eta  = (const float*)d_in[3];
    const float* s_zeta = (const float*)d_in[4];
    float* out = (float*)d_out;

    const int grid = 4464;  // 9 * 62 * 8 blocks of 448 threads
    hipLaunchKernelGGL(cns_residuals_kernel, dim3(grid), dim3(448), 0, stream,
                       vars, s_dx, s_dt, s_eta, s_zeta, out);
}

// Round 8
// 47.178 us; speedup vs baseline: 2.4774x; 1.0204x over previous
//
#include <hip/hip_runtime.h>

// CNS residuals: vars (B=8, C=4, T=64, X=128, Y=128) f32
// out (B=8, 2, 62, 126, 126) f32: [mass, mom_x+mom_y] on inner region.
// R8: vf2 / 4M-thread variant of R5. Evidence (R4<R5, R6/R7<R5): wave count
// (latency hiding) dominates load count. Halve per-thread y-width to 2,
// double threads. Lane j owns aligned 8B chunk {2j,2j+1}; outputs y=2j+1,2j+2.
// Windows: s=-1 free (own chunk), 2 shuffles for s=0/+1, 4 for Vw0 (+-2).
// Lane 63 computes garbage, stores nothing. XCD swizzle + NT stores kept.

typedef float vf2 __attribute__((ext_vector_type(2)));
typedef float vf2u __attribute__((ext_vector_type(2), aligned(4)));

__device__ __forceinline__ vf2 ld2(const float* p) {
    return *reinterpret_cast<const vf2u*>(p);
}

// window shifts for outputs y = 2j+1, 2j+2 from aligned chunk v = {2j, 2j+1}
struct W3 { vf2 c, p, m; };           // center, y+1, y-1
__device__ __forceinline__ W3 win(vf2 v) {
    const float d0 = __shfl_down(v.x, 1);
    const float d1 = __shfl_down(v.y, 1);
    W3 w;
    w.c = (vf2){v.y, d0};
    w.p = (vf2){d0, d1};
    w.m = v;
    return w;
}
struct W5 { vf2 c, p, m, p2, m2; };   // + y+2, y-2
__device__ __forceinline__ W5 win5(vf2 v, float mLo, float mD2) {
    const float um = __shfl_up(v.y, 1) * mLo;
    const float d0 = __shfl_down(v.x, 1);
    const float d1 = __shfl_down(v.y, 1);
    const float d2 = __shfl_down(v.x, 2) * mD2;
    W5 w;
    w.c  = (vf2){v.y, d0};
    w.p  = (vf2){d0, d1};
    w.m  = v;
    w.p2 = (vf2){d1, d2};
    w.m2 = (vf2){um, v.x};
    return w;
}

__global__ __launch_bounds__(256) void cns_residuals_kernel(
    const float* __restrict__ vars,
    const float* __restrict__ s_dx, const float* __restrict__ s_dt,
    const float* __restrict__ s_eta, const float* __restrict__ s_zeta,
    float* __restrict__ out)
{
    const float dx = s_dx[0], dt = s_dt[0], eta = s_eta[0], zeta = s_zeta[0];
    const float bulk = zeta + eta * (1.0f / 3.0f);
    const float c1 = 2.0f * dx * dx;
    const float c2 = 2.0f * dt * dx;
    const float c3 = 4.0f * dt;
    const float c4 = 2.0f * dt;

    // XCD-chunked bijective swizzle: nwg = 15624 = 8 * 1953 exactly
    const int i = blockIdx.x;
    const int lb = (i & 7) * 1953 + (i >> 3);

    const int tid = lb * 256 + threadIdx.x;
    const int j = tid & 63;            // lane; owns y' = {2j, 2j+1}
    int r = tid >> 6;
    const int xp = r % 126; r /= 126;
    const int tp = r % 62;  const int b = r / 62;
    const int x = xp + 1, t = tp + 1;
    const int q = 2 * j;

    const size_t plane = 16384;                 // 128*128
    const size_t cstr  = (size_t)64 * plane;

    const float* baseA = vars + (size_t)b * 4 * cstr + (size_t)t * plane
                       + ((size_t)x << 7) + q;
    const float* Rrow = baseA;
    const float* Urow = baseA + cstr;
    const float* Vrow = baseA + 2 * cstr;
    const float* Prow = baseA + 3 * cstr;

    const float mLo = (j == 0)  ? 0.0f : 1.0f;   // y' = -1 reads 0
    const float mD2 = (j >= 62) ? 0.0f : 1.0f;   // y' = 128 reads 0 (lane 62)

    // windows: aligned 8B load + 2 (or 4) shuffles each
    const W3 Rw  = win(ld2(Rrow));
    const W3 Uwm = win(ld2(Urow - 128));
    const W3 Uw0 = win(ld2(Urow));
    const W3 Uw1 = win(ld2(Urow + 128));
    const W3 Vwm = win(ld2(Vrow - 128));
    const W5 Vw0 = win5(ld2(Vrow), mLo, mD2);
    const W3 Vw1 = win(ld2(Vrow + 128));
    const W3 Pw  = win(ld2(Prow));

    // center-only loads at y = 2j+1 (misaligned 8B; lane-63 garbage unused)
    const vf2 rxp = ld2(Rrow + 129),  rxm = ld2(Rrow - 127);
    const vf2 pxp = ld2(Prow + 129),  pxm = ld2(Prow - 127);
    const vf2 rtp = ld2(Rrow + plane + 1), rtm = ld2(Rrow - plane + 1);
    const vf2 utp = ld2(Urow + plane + 1), utm = ld2(Urow - plane + 1);
    const vf2 vtp = ld2(Vrow + plane + 1), vtm = ld2(Vrow - plane + 1);
    const vf2 zero = {0.0f, 0.0f};
    const vf2 uxp2 = (x <= 125) ? ld2(Urow + 257) : zero;
    const vf2 uxm2 = (x >= 2)   ? ld2(Urow - 255) : zero;

    const vf2 rho = Rw.c;
    const vf2 u   = Uw0.c;
    const vf2 v   = Vw0.c;

    const vf2 uxp = Uw1.c, uxm = Uwm.c;
    const vf2 uyp = Uw0.p, uym = Uw0.m;
    const vf2 vxp = Vw1.c, vxm = Vwm.c;
    const vf2 vyp = Vw0.p, vym = Vw0.m;

    const vf2 Dt_rho = rtp - rtm;
    const vf2 Dx_rho = rxp - rxm;
    const vf2 Dy_rho = Rw.p - Rw.m;
    const vf2 Dx_u = uxp - uxm, Dy_u = uyp - uym;
    const vf2 Dx_v = vxp - vxm, Dy_v = vyp - vym;

    const vf2 mass = Dt_rho * dx + rho * (Dx_u + Dy_v) * dt
                   + u * Dx_rho * dt + v * Dy_rho * dt;

    const vf2 Dt_u = utp - utm, Dt_v = vtp - vtm;
    const vf2 Dx_p = pxp - pxm;
    const vf2 Dy_p = Pw.p - Pw.m;
    const vf2 lap_u = uxp + uxm + uyp + uym - 4.0f * u;
    const vf2 lap_v = vxp + vxm + vyp + vym - 4.0f * v;

    const vf2 Dx_div = uxp2 - 2.0f * u + uxm2
                     + Vw1.p - Vw1.m - Vwm.p + Vwm.m;
    const vf2 Dy_div = Vw0.p2 - 2.0f * v + Vw0.m2
                     + Uw1.p - Uwm.p - Uw1.m + Uwm.m;

    const vf2 mom = rho * (Dt_u + Dt_v) * c1
                  + (u * (Dx_u + Dx_v) + v * (Dy_u + Dy_v)) * c2
                  + (Dx_p + Dy_p) * c2
                  - eta * (lap_u + lap_v) * c3
                  - bulk * (Dx_div + Dy_div) * c4;

    const size_t oplane = 126 * 126;
    const size_t ocstr  = (size_t)62 * oplane;
    float* o1 = out + (size_t)b * 2 * ocstr + (size_t)tp * oplane
              + (size_t)xp * 126 + q;
    float* o2 = o1 + ocstr;
    if (j < 63) {  // lane 63's outputs (y=127,128) are out of range
        __builtin_nontemporal_store(mass, reinterpret_cast<vf2u*>(o1));
        __builtin_nontemporal_store(mom,  reinterpret_cast<vf2u*>(o2));
    }
}

extern "C" void kernel_launch(void* const* d_in, const int* in_sizes, int n_in,
                              void* d_out, int out_size, void* d_ws, size_t ws_size,
                              hipStream_t stream) {
    const float* vars   = (const float*)d_in[0];
    const float* s_dx   = (const float*)d_in[1];
    const float* s_dt   = (const float*)d_in[2];
    const float* s_eta  = (const float*)d_in[3];
    const float* s_zeta = (const float*)d_in[4];
    float* out = (float*)d_out;

    const int grid = 15624;  // 8*62*126*64 threads / 256
    hipLaunchKernelGGL(cns_residuals_kernel, dim3(grid), dim3(256), 0, stream,
                       vars, s_dx, s_dt, s_eta, s_zeta, out);
}

// Round 9
// 36.078 us; speedup vs baseline: 3.2396x; 1.3077x over previous
//
#include <hip/hip_runtime.h>

// CNS residuals: vars (B=8, C=4, T=64, X=128, Y=128) f32
// out (B=8, 2, 62, 126, 126) f32: [mass, mom_x+mom_y] inner region.
// R9 = R5 + half-wave x-row sharing. A wave's halves handle rows x0 (lanes
// 0-31) and x0+1 (lanes 32-63), same tile (xp0 even, 126 even). Each lane
// loads: own-center rows (R,U,V,P), exclusive row x+2h-1, U-outer x+4h-2;
// the missing x-neighbor rows come from __shfl_xor(.,32) half-swaps.
// x-sums need no fixup; x-diffs flip sign per half -> sign folded into
// per-thread scalar coefficients. Loads 20 -> 15/thread, all x-loads aligned.
// Keeps XCD-chunked swizzle + NT stores.

typedef float vf4 __attribute__((ext_vector_type(4)));
typedef float vf4u __attribute__((ext_vector_type(4), aligned(4)));

__device__ __forceinline__ vf4 ld4(const float* p) {
    return *reinterpret_cast<const vf4u*>(p);
}

struct Win { vf4 lo, hi; };
// window covers y' = 4j-1 .. 4j+6; output elem e at shift s -> index 2+e+s
#define SH(w, s) __builtin_shufflevector((w).lo, (w).hi, 2 + (s), 3 + (s), 4 + (s), 5 + (s))

__device__ __forceinline__ Win mkwin(vf4 c, float mHi) {
    const float dn0 = __shfl_down(c.x, 1) * mHi;
    const float dn1 = __shfl_down(c.y, 1) * mHi;
    Win w;
    w.lo = (vf4){0.0f, c.x, c.y, c.z};
    w.hi = (vf4){c.w, dn0, dn1, 0.0f};
    return w;
}
__device__ __forceinline__ Win mkwin2(vf4 c, float mLo, float mHi) {
    const float up3 = __shfl_up(c.w, 1) * mLo;
    const float dn0 = __shfl_down(c.x, 1) * mHi;
    const float dn1 = __shfl_down(c.y, 1) * mHi;
    const float dn2 = __shfl_down(c.z, 1) * mHi;
    Win w;
    w.lo = (vf4){up3, c.x, c.y, c.z};
    w.hi = (vf4){c.w, dn0, dn1, dn2};
    return w;
}
// center values y = 4j+1..4j+4 from an aligned chunk
__device__ __forceinline__ vf4 ctrf(vf4 c, float mHi) {
    const float dn0 = __shfl_down(c.x, 1) * mHi;
    return (vf4){c.y, c.z, c.w, dn0};
}
// other half's same-j value
__device__ __forceinline__ vf4 swap4(vf4 c) {
    vf4 r;
    r.x = __shfl_xor(c.x, 32);
    r.y = __shfl_xor(c.y, 32);
    r.z = __shfl_xor(c.z, 32);
    r.w = __shfl_xor(c.w, 32);
    return r;
}

__global__ __launch_bounds__(256) void cns_residuals_kernel(
    const float* __restrict__ vars,
    const float* __restrict__ s_dx, const float* __restrict__ s_dt,
    const float* __restrict__ s_eta, const float* __restrict__ s_zeta,
    float* __restrict__ out)
{
    const float dx = s_dx[0], dt = s_dt[0], eta = s_eta[0], zeta = s_zeta[0];
    const float bulk = zeta + eta * (1.0f / 3.0f);
    const float c1 = 2.0f * dx * dx;
    const float c2 = 2.0f * dt * dx;
    const float c3 = 4.0f * dt;
    const float c4 = 2.0f * dt;
    const float bc4 = bulk * c4;

    // XCD-chunked bijective swizzle: nwg = 7812 = 8*976 + 4
    const int i = blockIdx.x;
    const int xcd = i & 7;
    const int slot = i >> 3;
    const int lb = ((xcd < 4) ? xcd * 977 : 3908 + (xcd - 4) * 976) + slot;

    const int tid = lb * 256 + threadIdx.x;
    const int j = tid & 31;            // y-group: outputs y = 4j+1 .. 4j+4
    int r = tid >> 5;
    const int xp = r % 126; r /= 126;
    const int tp = r % 62;  const int b = r / 62;
    const int x = xp + 1, t = tp + 1;
    const int q = 4 * j;
    const int h = (threadIdx.x >> 5) & 1;   // half: row x0 (0) / x0+1 (1)

    // per-half sign for x-differences
    const float ssgn = h ? -1.0f : 1.0f;
    const float dts  = dt * ssgn;
    const float c2s  = c2 * ssgn;
    const float bc4s = bc4 * ssgn;

    const size_t plane = 16384;                 // 128*128
    const size_t cstr  = (size_t)64 * plane;

    const float* Rch = vars + (size_t)b * 4 * cstr + (size_t)t * plane;
    const float* Uch = Rch + cstr;
    const float* Vch = Rch + 2 * cstr;
    const float* Pch = Rch + 3 * cstr;

    const int xe = x + 2 * h - 1;      // exclusive row: h0 -> x-1, h1 -> x+1
    const int xo = x + 4 * h - 2;      // U outer row:  h0 -> x-2, h1 -> x+2

    // ---- 9 aligned x-row loads ----
    const vf4 R_c = ld4(Rch + ((size_t)x  << 7) + q);
    const vf4 R_e = ld4(Rch + ((size_t)xe << 7) + q);
    const vf4 U_c = ld4(Uch + ((size_t)x  << 7) + q);
    const vf4 U_i = ld4(Uch + ((size_t)xe << 7) + q);
    vf4 U_o = {0.0f, 0.0f, 0.0f, 0.0f};
    if ((unsigned)xo < 128u) U_o = ld4(Uch + ((size_t)xo << 7) + q);
    const vf4 V_c = ld4(Vch + ((size_t)x  << 7) + q);
    const vf4 V_e = ld4(Vch + ((size_t)xe << 7) + q);
    const vf4 P_c = ld4(Pch + ((size_t)x  << 7) + q);
    const vf4 P_e = ld4(Pch + ((size_t)xe << 7) + q);

    // ---- 6 t+-1 center loads (misaligned, unchanged from R5) ----
    const float* rowR = Rch + ((size_t)x << 7) + q + 1;
    const vf4 rtp = ld4(rowR + plane),            rtm = ld4(rowR - plane);
    const vf4 utp = ld4(rowR + cstr + plane),     utm = ld4(rowR + cstr - plane);
    const vf4 vtp = ld4(rowR + 2 * cstr + plane), vtm = ld4(rowR + 2 * cstr - plane);

    const float mLo = (j == 0)  ? 0.0f : 1.0f;   // y' = -1 reads 0
    const float mHi = (j == 31) ? 0.0f : 1.0f;   // y' >= 128 reads 0

    // ---- half-swaps (5 x 4 shfl_xor) ----
    const vf4 Rcs = swap4(R_c);
    const vf4 Pcs = swap4(P_c);
    const vf4 Ucs = swap4(U_c);
    const vf4 Uis = swap4(U_i);
    const vf4 Vcs = swap4(V_c);

    // ---- windows ----
    const Win Rw  = mkwin(R_c, mHi);
    const Win Pw  = mkwin(P_c, mHi);
    const Win Uw0 = mkwin(U_c, mHi);
    const Win Vw0 = mkwin2(V_c, mLo, mHi);
    const Win Au  = mkwin(U_i, mHi);   // h0: row x-1 | h1: row x+2
    const Win Bu  = mkwin(Ucs, mHi);   // h0: row x+1 | h1: row x
    const Win Av  = mkwin(V_e, mHi);
    const Win Bv  = mkwin(Vcs, mHi);

    const vf4 rho = SH(Rw, 0);
    const vf4 u   = SH(Uw0, 0);
    const vf4 v   = SH(Vw0, 0);
    const vf4 uyp = SH(Uw0, 1), uym = SH(Uw0, -1);
    const vf4 vyp = SH(Vw0, 1), vym = SH(Vw0, -1);

    // x-neighbor centers: B = (h? xm : xp), A = (h? xp : xm)
    const vf4 au = SH(Au, 0), bu = SH(Bu, 0);
    const vf4 av = SH(Av, 0), bv = SH(Bv, 0);
    const vf4 sum_ux = au + bu;                  // uxp + uxm (sign-free)
    const vf4 sum_vx = av + bv;                  // vxp + vxm
    const vf4 rawDx_u = bu - au;                 // ssgn * Dx_u
    const vf4 rawDx_v = bv - av;                 // ssgn * Dx_v

    const vf4 rawDx_rho = ctrf(Rcs - R_e, mHi);  // ssgn * Dx_rho
    const vf4 rawDx_p   = ctrf(Pcs - P_e, mHi);  // ssgn * Dx_p
    const vf4 usum2     = ctrf(U_o + Uis, mHi);  // u(x+2) + u(x-2) (sign-free)

    const vf4 Dy_rho = SH(Rw, 1) - SH(Rw, -1);
    const vf4 Dy_p   = SH(Pw, 1) - SH(Pw, -1);
    const vf4 Dy_u   = uyp - uym;
    const vf4 Dy_v   = vyp - vym;

    const vf4 lap_u = sum_ux + uyp + uym - 4.0f * u;
    const vf4 lap_v = sum_vx + vyp + vym - 4.0f * v;

    // div derivatives: split into sign-free and signed parts
    const vf4 unsignedDiv = (usum2 - 2.0f * u)
                          + (SH(Vw0, 2) - 2.0f * v + SH(Vw0, -2));
    const vf4 signedDiv = (SH(Bv, 1) - SH(Bv, -1)) - (SH(Av, 1) - SH(Av, -1))
                        + (SH(Bu, 1) - SH(Bu, -1)) - (SH(Au, 1) - SH(Au, -1));

    const vf4 Dt_rho = rtp - rtm;
    const vf4 Dt_u = utp - utm, Dt_v = vtp - vtm;

    const vf4 mass = Dt_rho * dx
                   + (rho * rawDx_u + u * rawDx_rho) * dts
                   + (rho * Dy_v + v * Dy_rho) * dt;

    const vf4 mom = rho * (Dt_u + Dt_v) * c1
                  + (u * (rawDx_u + rawDx_v) + rawDx_p) * c2s
                  + (v * (Dy_u + Dy_v) + Dy_p) * c2
                  - eta * (lap_u + lap_v) * c3
                  - bc4 * unsignedDiv - bc4s * signedDiv;

    const size_t oplane = 126 * 126;
    const size_t ocstr  = (size_t)62 * oplane;
    float* o1 = out + (size_t)b * 2 * ocstr + (size_t)tp * oplane
              + (size_t)xp * 126 + q;
    float* o2 = o1 + ocstr;
    if (j < 31) {
        __builtin_nontemporal_store(mass, reinterpret_cast<vf4u*>(o1));
        __builtin_nontemporal_store(mom,  reinterpret_cast<vf4u*>(o2));
    } else {  // outputs y=127,128 out of range; store only 2
        __builtin_nontemporal_store(mass[0], o1);
        __builtin_nontemporal_store(mass[1], o1 + 1);
        __builtin_nontemporal_store(mom[0],  o2);
        __builtin_nontemporal_store(mom[1],  o2 + 1);
    }
}

extern "C" void kernel_launch(void* const* d_in, const int* in_sizes, int n_in,
                              void* d_out, int out_size, void* d_ws, size_t ws_size,
                              hipStream_t stream) {
    const float* vars   = (const float*)d_in[0];
    const float* s_dx   = (const float*)d_in[1];
    const float* s_dt   = (const float*)d_in[2];
    const float* s_eta  = (const float*)d_in[3];
    const float* s_zeta = (const float*)d_in[4];
    float* out = (float*)d_out;

    const int grid = 7812;  // 8*62*126*32 threads / 256
    hipLaunchKernelGGL(cns_residuals_kernel, dim3(grid), dim3(256), 0, stream,
                       vars, s_dx, s_dt, s_eta, s_zeta, out);
}